// Round 17
// baseline (309.218 us; speedup 1.0000x reference)
//
#include <hip/hip_runtime.h>
#include <hip/hip_bf16.h>
#include <math.h>

#define TD 512      // D (feature dim)
#define TH 64       // H (hidden dim)
#define CHUNK 16    // rows per chunk
#define NT 256      // threads per block (4 waves); target 4 blocks/CU

typedef __attribute__((ext_vector_type(8))) short bf16x8;
typedef __attribute__((ext_vector_type(4))) float f32x4;

__device__ __forceinline__ unsigned short f2b(float f) {
    return __builtin_bit_cast(unsigned short, __float2bfloat16(f));
}

__device__ __forceinline__ float tanh_fast(float v) {
    float e = __expf(2.0f * v);
    return 1.0f - 2.0f / (e + 1.0f);
}

// Barrier that drains LDS ops only — global loads stay in flight.
__device__ __forceinline__ void barrier_lgkm() {
    asm volatile("s_waitcnt lgkmcnt(0)" ::: "memory");
    __builtin_amdgcn_s_barrier();
}

// Pure-VALU 16-lane-group sum via DPP row rotates (validated R9-R16).
template <int CTRL>
__device__ __forceinline__ float dpp_add(float v) {
    int r = __builtin_amdgcn_update_dpp(0, __builtin_bit_cast(int, v), CTRL, 0xf, 0xf, false);
    return v + __builtin_bit_cast(float, r);
}
__device__ __forceinline__ float row16_sum(float v) {
    v = dpp_add<0x121>(v);   // row_ror:1
    v = dpp_add<0x122>(v);   // row_ror:2
    v = dpp_add<0x124>(v);   // row_ror:4
    v = dpp_add<0x128>(v);   // row_ror:8
    return v;
}

// Prep: segment offsets off[0..B], W1 -> bf16 [col][k] (64 KB in d_ws),
// zero the atomic accumulators (out, denom).
__global__ void prep_kernel(const int* __restrict__ batch32,
                            const float* __restrict__ W1,
                            int* __restrict__ off,
                            unsigned short* __restrict__ W1B,
                            float* __restrict__ outp,
                            float* __restrict__ denom,
                            int N, int B) {
    int i = blockIdx.x * blockDim.x + threadIdx.x;
    if (i < B * TD) outp[i] = 0.0f;
    if (i < B) denom[i] = 0.0f;
    if (i < TH * TD) {
        int c = i >> 9;          // col 0..63
        int k = i & 511;         // k   0..511
        W1B[i] = f2b(W1[k * TH + c]);
    }
    if (i >= N) return;
    const bool is64 = (batch32[N - 1] == 0);   // int64 LE => word N-1 is a high word == 0
    auto bval = [&](int kk) -> int { return is64 ? batch32[2 * kk] : batch32[kk]; };
    int bc = bval(i);
    if (i == 0) {
        for (int j = 0; j <= bc; ++j) off[j] = 0;
    } else {
        int bp = bval(i - 1);
        for (int j = bp + 1; j <= bc; ++j) off[j] = i;
    }
    if (i == N - 1) {
        for (int j = bc + 1; j <= B; ++j) off[j] = N;
    }
}

// Normalize: out = partials / (denom + eps)
__global__ void norm_kernel(float* __restrict__ outp,
                            const float* __restrict__ denom, int total) {
    int i = blockIdx.x * blockDim.x + threadIdx.x;
    if (i < total) outp[i] = outp[i] / (denom[i >> 9] + 1e-16f);   // TD=512
}

__global__ __launch_bounds__(NT, 4)
void attnpool_kernel(const float* __restrict__ x,
                     const unsigned short* __restrict__ W1B,
                     const float* __restrict__ b1,
                     const float* __restrict__ W2,
                     const float* __restrict__ b2,
                     const int* __restrict__ off,
                     float* __restrict__ outp,
                     float* __restrict__ denom,
                     int N)
{
    __shared__ __align__(16) unsigned short Atile[CHUNK * TD];   // 16 KB
    __shared__ float sP[4][CHUNK];

    const int tid  = threadIdx.x;
    const int b    = blockIdx.x >> 1;     // segment
    const int half = blockIdx.x & 1;      // half of the segment
    const int lane = tid & 63;
    const int ct   = tid >> 6;            // wave = coltile 0..3

    const int s0   = off[b];
    const int lful = off[b + 1] - s0;
    const int h0   = (lful + 1) >> 1;     // rows in half 0
    const int seg_start = half ? (s0 + h0) : s0;
    const int seg_len   = half ? (lful - h0) : h0;
    const float b2v = b2[0];

    const int rowcls = tid >> 7;          // 0..1 (wave-pair uniform)
    const int col4   = (tid & 127) << 2;  // feature column base (x4)

    const int jcol = (ct << 4) + (lane & 15);   // this wave's output column
    const int kb   = (lane >> 4) << 3;          // k-slice within MFMA frag
    const float b1v = b1[jcol];
    const float w2v = W2[jcol];

    float4 accw; accw.x = 0.f; accw.y = 0.f; accw.z = 0.f; accw.w = 0.f;
    float l_part = 0.0f;                  // wave 0 (ct==0), lanes 0..15
    float4 xrA[8], xrB[8];

    auto load_chunk = [&](float4 (&xr)[8], int c0) {
        #pragma unroll
        for (int p = 0; p < 8; ++p) {
            int rl = (p << 1) + rowcls;
            int r  = c0 + rl;
            int gr = (r < seg_len) ? (seg_start + r) : seg_start;  // clamp; pads get w=0
            xr[p] = *reinterpret_cast<const float4*>(&x[(size_t)gr * TD + col4]);
        }
    };

    if (seg_len > 0) load_chunk(xrA, 0);

    // ---- w1f fragments straight from L2-resident W1B (once, pre-loop) ----
    bf16x8 w1f[16];
    #pragma unroll
    for (int kk = 0; kk < 16; ++kk) {
        w1f[kk] = *reinterpret_cast<const bf16x8*>(&W1B[jcol * TD + (kk << 5) + kb]);
    }

    auto body = [&](float4 (&cur)[8], float4 (&nxt)[8], int c0) {
        // (1) prefetch FIRST — the ONLY vmem in the steady loop; stays
        //     outstanding across all lgkm-only barriers below.
        if (c0 + CHUNK < seg_len) load_chunk(nxt, c0 + CHUNK);

        // (2) convert + store A tile (swizzled); waits only on cur's loads
        #pragma unroll
        for (int p = 0; p < 8; ++p) {
            int rl = (p << 1) + rowcls;
            ushort4 v;
            v.x = f2b(cur[p].x); v.y = f2b(cur[p].y);
            v.z = f2b(cur[p].z); v.w = f2b(cur[p].w);
            *reinterpret_cast<ushort4*>(&Atile[(rl * TD + col4) ^ ((rl & 7) << 3)]) = v;
        }
        barrier_lgkm();   // #1: Atile ready

        // (3) MFMA: rows 0..15 x this wave's 16 cols; A from LDS, B from regs
        f32x4 acc = {0, 0, 0, 0};
        const int rA = lane & 15;
        #pragma unroll
        for (int kk = 0; kk < 16; ++kk) {
            int k0 = (kk << 5) + kb;
            bf16x8 av = *reinterpret_cast<const bf16x8*>(
                &Atile[(rA * TD + k0) ^ ((rA & 7) << 3)]);
            acc = __builtin_amdgcn_mfma_f32_16x16x32_bf16(av, w1f[kk], acc, 0, 0, 0);
        }

        // (4) bias + tanh + *W2; DPP 16-lane row sum (VALU only); write sP
        {
            float pv[4];
            #pragma unroll
            for (int q = 0; q < 4; ++q)
                pv[q] = row16_sum(tanh_fast(acc[q] + b1v) * w2v);
            if ((lane & 15) == 0) {
                int g = lane >> 4;
                #pragma unroll
                for (int q = 0; q < 4; ++q)
                    sP[ct][(g << 2) + q] = pv[q];
            }
        }
        barrier_lgkm();   // #2: sP ready (LAST barrier this chunk)

        // (5) redundant per-wave direct exp (|s| <= sum|W2|+|b2| ~ 4.3):
        //     identical in all waves; r = lane&15 covers rows 0..15 four times.
        float ev;
        {
            int r = lane & 15;
            float s = sP[0][r] + sP[1][r] + sP[2][r] + sP[3][r] + b2v;
            ev = ((c0 + r) < seg_len) ? __expf(s) : 0.0f;
            if (ct == 0 && lane < CHUNK) l_part += ev;
        }

        // (6) weighted accumulation; wgt via wave-uniform shfl (readlane bcast)
        #pragma unroll
        for (int p = 0; p < 8; ++p) {
            float wgt = __shfl(ev, (p << 1) + rowcls, 64);
            accw.x += wgt * cur[p].x;
            accw.y += wgt * cur[p].y;
            accw.z += wgt * cur[p].z;
            accw.w += wgt * cur[p].w;
        }
    };

    if (seg_len > 0) {
        int c0 = 0;
        while (true) {
            body(xrA, xrB, c0);
            c0 += CHUNK;
            if (c0 >= seg_len) break;
            body(xrB, xrA, c0);
            c0 += CHUNK;
            if (c0 >= seg_len) break;
        }

        // ---- epilogue: atomic partial combine (2 blocks per segment) ----
        atomicAdd(&outp[(size_t)b * TD + col4 + 0], accw.x);
        atomicAdd(&outp[(size_t)b * TD + col4 + 1], accw.y);
        atomicAdd(&outp[(size_t)b * TD + col4 + 2], accw.z);
        atomicAdd(&outp[(size_t)b * TD + col4 + 3], accw.w);
        if (ct == 0) {
            float ls = row16_sum(l_part);   // lanes 0..15 -> lane0 holds sum
            if (lane == 0) atomicAdd(&denom[b], ls);
        }
    }
}

extern "C" void kernel_launch(void* const* d_in, const int* in_sizes, int n_in,
                              void* d_out, int out_size, void* d_ws, size_t ws_size,
                              hipStream_t stream) {
    const float* x  = (const float*)d_in[0];
    const float* W1 = (const float*)d_in[1];
    const float* b1 = (const float*)d_in[2];
    const float* W2 = (const float*)d_in[3];
    const float* b2 = (const float*)d_in[4];
    const int* batch = (const int*)d_in[5];
    int N = in_sizes[5];
    int B = out_size / TD;
    if (B <= 0 || N <= 0) return;

    int* off = (int*)d_ws;                                         // B+1 ints
    unsigned short* W1B = (unsigned short*)((char*)d_ws + 4096);   // 64 KB bf16 W1^T
    float* denom = (float*)((char*)d_ws + 4096 + TH * TD * 2);     // B floats
    float* outp  = (float*)d_out;

    int prep_elems = N;
    if (B * TD > prep_elems) prep_elems = B * TD;
    if (TH * TD > prep_elems) prep_elems = TH * TD;
    prep_kernel<<<dim3((prep_elems + 255) / 256), dim3(256), 0, stream>>>(
        batch, W1, off, W1B, outp, denom, N, B);
    attnpool_kernel<<<dim3(2 * B), dim3(NT), 0, stream>>>(
        x, W1B, b1, W2, b2, off, outp, denom, N);
    norm_kernel<<<dim3((B * TD + 255) / 256), dim3(256), 0, stream>>>(
        outp, denom, B * TD);
}

// Round 18
// 87.257 us; speedup vs baseline: 3.5438x; 3.5438x over previous
//
#include <hip/hip_runtime.h>
#include <hip/hip_bf16.h>
#include <math.h>

#define TD 512      // D (feature dim)
#define TH 64       // H (hidden dim)
#define CHUNK 16    // rows per chunk
#define NT 256      // threads per block (4 waves); 2 blocks/CU

typedef __attribute__((ext_vector_type(8))) short bf16x8;
typedef __attribute__((ext_vector_type(4))) float f32x4;

__device__ __forceinline__ unsigned short f2b(float f) {
    return __builtin_bit_cast(unsigned short, __float2bfloat16(f));
}

__device__ __forceinline__ float tanh_fast(float v) {
    float e = __expf(2.0f * v);
    return 1.0f - 2.0f / (e + 1.0f);
}

// Barrier that drains LDS ops only — global loads stay in flight.
__device__ __forceinline__ void barrier_lgkm() {
    asm volatile("s_waitcnt lgkmcnt(0)" ::: "memory");
    __builtin_amdgcn_s_barrier();
}

// Pure-VALU 16-lane-group sum via DPP row rotates (validated R9-R16).
template <int CTRL>
__device__ __forceinline__ float dpp_add(float v) {
    int r = __builtin_amdgcn_update_dpp(0, __builtin_bit_cast(int, v), CTRL, 0xf, 0xf, false);
    return v + __builtin_bit_cast(float, r);
}
__device__ __forceinline__ float row16_sum(float v) {
    v = dpp_add<0x121>(v);   // row_ror:1
    v = dpp_add<0x122>(v);   // row_ror:2
    v = dpp_add<0x124>(v);   // row_ror:4
    v = dpp_add<0x128>(v);   // row_ror:8
    return v;
}

// Prep: segment offsets off[0..B] + W1 -> bf16 [col][k] (64 KB in d_ws).
__global__ void prep_kernel(const int* __restrict__ batch32,
                            const float* __restrict__ W1,
                            int* __restrict__ off,
                            unsigned short* __restrict__ W1B,
                            int N, int B) {
    int i = blockIdx.x * blockDim.x + threadIdx.x;
    if (i < TH * TD) {
        int c = i >> 9;          // col 0..63
        int k = i & 511;         // k   0..511
        W1B[i] = f2b(W1[k * TH + c]);
    }
    if (i >= N) return;
    const bool is64 = (batch32[N - 1] == 0);   // int64 LE => word N-1 is a high word == 0
    auto bval = [&](int kk) -> int { return is64 ? batch32[2 * kk] : batch32[kk]; };
    int bc = bval(i);
    if (i == 0) {
        for (int j = 0; j <= bc; ++j) off[j] = 0;
    } else {
        int bp = bval(i - 1);
        for (int j = bp + 1; j <= bc; ++j) off[j] = i;
    }
    if (i == N - 1) {
        for (int j = bc + 1; j <= B; ++j) off[j] = N;
    }
}

__global__ __launch_bounds__(NT)
__attribute__((amdgpu_waves_per_eu(2, 2)))
void attnpool_kernel(const float* __restrict__ x,
                     const unsigned short* __restrict__ W1B,
                     const float* __restrict__ b1,
                     const float* __restrict__ W2,
                     const float* __restrict__ b2,
                     const int* __restrict__ off,
                     float* __restrict__ out,
                     int N)
{
    // 64 KB union: W1T (bf16 [col][k], swizzled) during init; Atile afterwards.
    __shared__ __align__(16) char smem[TH * TD * 2];
    __shared__ float sP[4][CHUNK];
    __shared__ float lsum;
    unsigned short* W1T   = (unsigned short*)smem;
    unsigned short* Atile = (unsigned short*)smem;   // CHUNK*TD*2 = 16 KB of it

    const int tid  = threadIdx.x;
    const int b    = blockIdx.x;
    const int lane = tid & 63;
    const int ct   = tid >> 6;            // wave = coltile 0..3

    const int seg_start = off[b];
    const int seg_len   = off[b + 1] - seg_start;
    const float b2v = b2[0];

    const int rowcls = tid >> 7;          // 0..1 (wave-pair uniform)
    const int col4   = (tid & 127) << 2;  // feature column base (x4)

    const int jcol = (ct << 4) + (lane & 15);   // this wave's output column
    const int kb   = (lane >> 4) << 3;          // k-slice within MFMA frag
    const float b1v = b1[jcol];
    const float w2v = W2[jcol];

    float4 accw; accw.x = 0.f; accw.y = 0.f; accw.z = 0.f; accw.w = 0.f;
    float l_part = 0.0f;                  // wave 0 (ct==0), lanes 0..15
    float4 xrA[8], xrB[8];

    auto load_chunk = [&](float4 (&xr)[8], int c0) {
        #pragma unroll
        for (int p = 0; p < 8; ++p) {
            int rl = (p << 1) + rowcls;
            int r  = c0 + rl;
            int gr = (r < seg_len) ? (seg_start + r) : seg_start;  // clamp; pads get w=0
            xr[p] = *reinterpret_cast<const float4*>(&x[(size_t)gr * TD + col4]);
        }
    };

    if (seg_len > 0) load_chunk(xrA, 0);

    // ---- stage W1B (bf16, [col][k]) -> LDS W1T, coalesced b128, swizzled ----
    {
        const bf16x8* W1B8 = reinterpret_cast<const bf16x8*>(W1B);
        #pragma unroll
        for (int i = 0; i < (TH * TD / 8) / NT; ++i) {   // 16 iters
            int e8 = tid + NT * i;        // 16B-unit index
            int c  = e8 >> 6;             // col 0..63
            int k8 = e8 & 63;             // k-octet 0..63
            bf16x8 v = W1B8[e8];
            *reinterpret_cast<bf16x8*>(&W1T[(c * TD + (k8 << 3)) ^ ((c & 7) << 3)]) = v;
        }
    }
    barrier_lgkm();   // W1T ready

    // ---- each wave pulls its 16-col B-fragments into registers (64 VGPR) ----
    bf16x8 w1f[16];
    #pragma unroll
    for (int kk = 0; kk < 16; ++kk) {
        w1f[kk] = *reinterpret_cast<const bf16x8*>(
            &W1T[(jcol * TD + (kk << 5) + kb) ^ ((jcol & 7) << 3)]);
    }
    barrier_lgkm();   // all w1f reads done before Atile overwrites W1T

    auto body = [&](float4 (&cur)[8], float4 (&nxt)[8], int c0) {
        // (1) prefetch FIRST — the ONLY vmem in the steady loop; stays
        //     outstanding across all lgkm-only barriers below.
        if (c0 + CHUNK < seg_len) load_chunk(nxt, c0 + CHUNK);

        // (2) convert + store A tile (swizzled); waits only on cur's loads
        #pragma unroll
        for (int p = 0; p < 8; ++p) {
            int rl = (p << 1) + rowcls;
            ushort4 v;
            v.x = f2b(cur[p].x); v.y = f2b(cur[p].y);
            v.z = f2b(cur[p].z); v.w = f2b(cur[p].w);
            *reinterpret_cast<ushort4*>(&Atile[(rl * TD + col4) ^ ((rl & 7) << 3)]) = v;
        }
        barrier_lgkm();   // #1: Atile ready

        // (3) MFMA: rows 0..15 x this wave's 16 cols; A from LDS, B from regs
        f32x4 acc = {0, 0, 0, 0};
        const int rA = lane & 15;
        #pragma unroll
        for (int kk = 0; kk < 16; ++kk) {
            int k0 = (kk << 5) + kb;
            bf16x8 av = *reinterpret_cast<const bf16x8*>(
                &Atile[(rA * TD + k0) ^ ((rA & 7) << 3)]);
            acc = __builtin_amdgcn_mfma_f32_16x16x32_bf16(av, w1f[kk], acc, 0, 0, 0);
        }

        // (4) bias + tanh + *W2; DPP 16-lane row sum (VALU only); write sP
        {
            float pv[4];
            #pragma unroll
            for (int q = 0; q < 4; ++q)
                pv[q] = row16_sum(tanh_fast(acc[q] + b1v) * w2v);
            if ((lane & 15) == 0) {
                int g = lane >> 4;
                #pragma unroll
                for (int q = 0; q < 4; ++q)
                    sP[ct][(g << 2) + q] = pv[q];
            }
        }
        barrier_lgkm();   // #2: sP ready (LAST barrier this chunk)

        // (5) redundant per-wave direct exp (|s| <= sum|W2|+|b2| ~ 4.3):
        //     identical in all waves; r = lane&15 covers rows 0..15 four times.
        float ev;
        {
            int r = lane & 15;
            float s = sP[0][r] + sP[1][r] + sP[2][r] + sP[3][r] + b2v;
            ev = ((c0 + r) < seg_len) ? __expf(s) : 0.0f;
            if (ct == 0 && lane < CHUNK) l_part += ev;
        }

        // (6) weighted accumulation; wgt via wave-uniform shfl (readlane bcast)
        #pragma unroll
        for (int p = 0; p < 8; ++p) {
            float wgt = __shfl(ev, (p << 1) + rowcls, 64);
            accw.x += wgt * cur[p].x;
            accw.y += wgt * cur[p].y;
            accw.z += wgt * cur[p].z;
            accw.w += wgt * cur[p].w;
        }
    };

    if (seg_len > 0) {
        int c0 = 0;
        while (true) {
            body(xrA, xrB, c0);
            c0 += CHUNK;
            if (c0 >= seg_len) break;
            body(xrB, xrA, c0);
            c0 += CHUNK;
            if (c0 >= seg_len) break;
        }
    }

    // ---- epilogue: reuse Atile (dead) as [2][TD] float scratch ----
    float* fs = reinterpret_cast<float*>(Atile);
    __syncthreads();   // ensure all Atile reads done before float overwrite
    *reinterpret_cast<float4*>(&fs[rowcls * TD + col4]) = accw;
    if (ct == 0) {
        float ls = l_part;
        #pragma unroll
        for (int m = 1; m < 64; m <<= 1) ls += __shfl_xor(ls, m, 64);
        if (lane == 0) lsum = ls;
    }
    __syncthreads();
    float inv = 1.0f / (lsum + 1e-16f);
    out[(size_t)b * TD + tid]       = (fs[tid] + fs[TD + tid]) * inv;
    out[(size_t)b * TD + 256 + tid] = (fs[256 + tid] + fs[TD + 256 + tid]) * inv;
}

extern "C" void kernel_launch(void* const* d_in, const int* in_sizes, int n_in,
                              void* d_out, int out_size, void* d_ws, size_t ws_size,
                              hipStream_t stream) {
    const float* x  = (const float*)d_in[0];
    const float* W1 = (const float*)d_in[1];
    const float* b1 = (const float*)d_in[2];
    const float* W2 = (const float*)d_in[3];
    const float* b2 = (const float*)d_in[4];
    const int* batch = (const int*)d_in[5];
    int N = in_sizes[5];
    int B = out_size / TD;
    if (B <= 0 || N <= 0) return;

    int* off = (int*)d_ws;                                       // B+1 ints
    unsigned short* W1B = (unsigned short*)((char*)d_ws + 4096); // 64 KB bf16 W1^T

    int prep_elems = (N > TH * TD) ? N : TH * TD;
    prep_kernel<<<dim3((prep_elems + 255) / 256), dim3(256), 0, stream>>>(
        batch, W1, off, W1B, N, B);
    attnpool_kernel<<<dim3(B), dim3(NT), 0, stream>>>(
        x, W1B, b1, W2, b2, off, (float*)d_out, N);
}